// Round 8
// baseline (30337.234 us; speedup 1.0000x reference)
//
#include <hip/hip_runtime.h>

typedef __bf16 bf16x8 __attribute__((ext_vector_type(8)));
typedef float f32x4 __attribute__((ext_vector_type(4)));
typedef unsigned short u16;
typedef unsigned int u32;

#define MFMA16(a, b, c) __builtin_amdgcn_mfma_f32_16x16x32_bf16((a), (b), (c), 0, 0, 0)

// ---------------------------------------------------------------------------
// Row-tile groups: grid = 128 blocks = 8 groups x 16 blocks. Group g owns
// batch rows g*16..g*16+15 for the whole recurrence (the DAG is row-separable:
// every GEMM is s_p[rows,:] @ W). Cross-block sync is per-group only: a flat
// 16-participant AGENT/LLC epoch counter (round-2/4-proven counter class:
// memset-zeroed, never L2-dirty, replay-safe). State traffic: sc0sc1 LLC ops
// (round-4-proven). Weights: plain cached loads after sc1 init + one-time
// wbl2/inv hygiene (round-4-proven). All polls bounded (no hangs).
//
// counters (u32 idx; first 8192 B memset 0): global flat barrier at 512;
//   group g barrier at 1024 + g*64.
// ws u16 layout: Wh[5242880] @ byte 8192, Wl[5242880],
//   T[8 groups][8 slots][16384] (16 rows x 512 cols; hi-plane[8192]++lo[8192]).
// slots: 0=h 1=s0 2=s1 3=s2 4=s3 5=s4 6=s5 7=s7
// ---------------------------------------------------------------------------

__device__ __forceinline__ u16 f2bf(float f) {
  u32 u = __float_as_uint(f);
  u += 0x7FFFu + ((u >> 16) & 1u);
  return (u16)(u >> 16);
}
__device__ __forceinline__ float bf2f(u32 h) { return __uint_as_float(h << 16); }
__device__ __forceinline__ void splitbf(float f, u16 &hi, u16 &lo) {
  hi = f2bf(f);
  lo = f2bf(f - bf2f((u32)hi));
}

__device__ __forceinline__ void issue_ld128_sc(bf16x8 &d, const u16 *p) {
  asm volatile("global_load_dwordx4 %0, %1, off sc0 sc1" : "=v"(d) : "v"(p));
}
__device__ __forceinline__ void issue_ldu16_sc(u32 &d, const u16 *p) {
  asm volatile("global_load_ushort %0, %1, off sc0 sc1" : "=v"(d) : "v"(p));
}
__device__ __forceinline__ void wait_vm() {
  asm volatile("s_waitcnt vmcnt(0)" ::: "memory");
  __builtin_amdgcn_sched_barrier(0);
}
__device__ __forceinline__ void st16_sc(u16 *p, u16 v) {
  u32 q = v;
  asm volatile("global_store_short %0, %1, off sc0 sc1" :: "v"(p), "v"(q) : "memory");
}

__device__ __forceinline__ int mbase(int m) {          // u16 elems; m=0 -> W0 (K=1024)
  return m == 0 ? 0 : 1048576 + (m - 1) * 524288;
}
__device__ __forceinline__ int lineOf(int row, int scol) {
  return (scol >> 5) * 64 + row + ((scol >> 3) & 3) * 16;
}
__device__ __forceinline__ int goffG(int slot, int row, int scol) {  // hi; lo at +8192
  return slot * 16384 + lineOf(row, scol) * 8 + (scol & 7);
}

template <int A> __device__ __forceinline__ float actf(float x) {
  if (A == 0) { float e = __expf(2.f * x); return 1.f - 2.f / (e + 1.f); } // tanh
  if (A == 1) return 1.f / (1.f + __expf(-x));                            // sigmoid
  if (A == 2) return fmaxf(x, 0.f);                                       // relu
  return x;                                                               // identity
}

__device__ __forceinline__ float lds_elem(const u16 *lds, int row, int scol) {
  int o = lineOf(row, scol) * 8 + (scol & 7);
  return bf2f(lds[o]) + bf2f(lds[o + 8192]);
}

// copy one 32KB slot panel (group) global->LDS; layouts identical
__device__ __forceinline__ void stage_panel(const u16 *Sg, int slot, u16 *lds, int tid) {
  const u16 *src = Sg + slot * 16384 + tid * 8;
  bf16x8 r[8];
#pragma unroll
  for (int i = 0; i < 8; ++i) issue_ld128_sc(r[i], src + i * 2048);
  wait_vm();
#pragma unroll
  for (int i = 0; i < 8; ++i) *(bf16x8 *)(lds + tid * 8 + i * 2048) = r[i];
}

template <int ACT, bool STORE>
__device__ __forceinline__ void act2(f32x4 acc, const float *spv, u16 *Sg, int dslot,
                                     int cb, int l4, int l15, float *sv) {
#pragma unroll
  for (int j = 0; j < 4; ++j) {
    float cp = acc[j];
    float hp = __shfl_xor(cp, 1);
    float sig = 1.f / (1.f + __expf(-cp));
    float sval = spv[j] + sig * (actf<ACT>(hp) - spv[j]);
    sv[j] = sval;
    if (STORE && ((l15 & 1) == 0)) {
      int row = l4 * 4 + j, scol = cb * 8 + (l15 >> 1);
      u16 hi, lo; splitbf(sval, hi, lo);
      u16 *p = Sg + goffG(dslot, row, scol);
      st16_sc(p, hi);
      st16_sc(p + 8192, lo);
    }
  }
}

// K=512 GEMM; A-panel (and s_prev) from LDS; weights plain cached loads
template <int ACT0, int ACT1, bool TWO, bool ST>
__device__ __forceinline__ void gemm512(const u16 *Wh, const u16 *Wl, u16 *Sg, const u16 *lds,
                                        int m0, int m1, int d0, int d1,
                                        int cb, int ln, int l4, int l15,
                                        float *sv0, float *sv1) {
  float spv[4];
#pragma unroll
  for (int j = 0; j < 4; ++j) spv[j] = lds_elem(lds, l4 * 4 + j, cb * 8 + (l15 >> 1));
  f32x4 acc0 = {0.f, 0.f, 0.f, 0.f}, acc1 = {0.f, 0.f, 0.f, 0.f};
  const u16 *w0h = Wh + mbase(m0) + (cb * 16 * 64 + ln) * 8;
  const u16 *w0l = Wl + mbase(m0) + (cb * 16 * 64 + ln) * 8;
  const u16 *w1h = Wh + mbase(m1) + (cb * 16 * 64 + ln) * 8;
  const u16 *w1l = Wl + mbase(m1) + (cb * 16 * 64 + ln) * 8;
#pragma unroll
  for (int kc = 0; kc < 16; ++kc) {
    bf16x8 Ah = *(const bf16x8 *)(lds + (kc * 64 + ln) * 8);
    bf16x8 Al = *(const bf16x8 *)(lds + 8192 + (kc * 64 + ln) * 8);
    bf16x8 b0h = *(const bf16x8 *)(w0h + kc * 512);
    bf16x8 b0l = *(const bf16x8 *)(w0l + kc * 512);
    acc0 = MFMA16(Ah, b0h, acc0);
    acc0 = MFMA16(Ah, b0l, acc0);
    acc0 = MFMA16(Al, b0h, acc0);
    if (TWO) {
      bf16x8 b1h = *(const bf16x8 *)(w1h + kc * 512);
      bf16x8 b1l = *(const bf16x8 *)(w1l + kc * 512);
      acc1 = MFMA16(Ah, b1h, acc1);
      acc1 = MFMA16(Ah, b1l, acc1);
      acc1 = MFMA16(Al, b1h, acc1);
    }
  }
  act2<ACT0, ST>(acc0, spv, Sg, d0, cb, l4, l15, sv0);
  if (TWO) act2<ACT1, ST>(acc1, spv, Sg, d1, cb, l4, l15, sv1);
}

// round A: s0 = h + sigmoid(c)*(tanh(h') - h); A = [x_t | h], K=1024, W0.
// x read directly from global (plain cached, round-4-proven); h from LDS panel.
__device__ __forceinline__ void roundA(const float *xin, int t, int trow0,
                                       const u16 *Wh, const u16 *Wl, u16 *Sg, const u16 *lds,
                                       int cb, int ln, int l4, int l15) {
  float spv[4];
#pragma unroll
  for (int j = 0; j < 4; ++j) spv[j] = lds_elem(lds, l4 * 4 + j, cb * 8 + (l15 >> 1));
  f32x4 acc = {0.f, 0.f, 0.f, 0.f};
  const u16 *wh = Wh + (cb * 32 * 64 + ln) * 8;
  const u16 *wl = Wl + (cb * 32 * 64 + ln) * 8;
  const float *xp = xin + (t * 128 + trow0 + l15) * 512 + l4 * 8;
#pragma unroll
  for (int kc = 0; kc < 16; ++kc) {  // x half (k<512), on-the-fly split
    f32x4 xa = *(const f32x4 *)(xp + kc * 32);
    f32x4 xb = *(const f32x4 *)(xp + kc * 32 + 4);
    union { u16 u[8]; bf16x8 v; } H, Lo;
#pragma unroll
    for (int e = 0; e < 4; ++e) {
      splitbf(xa[e], H.u[e], Lo.u[e]);
      splitbf(xb[e], H.u[4 + e], Lo.u[4 + e]);
    }
    bf16x8 bh = *(const bf16x8 *)(wh + kc * 512);
    bf16x8 bl = *(const bf16x8 *)(wl + kc * 512);
    acc = MFMA16(H.v, bh, acc);
    acc = MFMA16(H.v, bl, acc);
    acc = MFMA16(Lo.v, bh, acc);
  }
#pragma unroll
  for (int kc = 0; kc < 16; ++kc) {  // h half (k>=512), from LDS
    bf16x8 Ah = *(const bf16x8 *)(lds + (kc * 64 + ln) * 8);
    bf16x8 Al = *(const bf16x8 *)(lds + 8192 + (kc * 64 + ln) * 8);
    bf16x8 bh = *(const bf16x8 *)(wh + (16 + kc) * 512);
    bf16x8 bl = *(const bf16x8 *)(wl + (16 + kc) * 512);
    acc = MFMA16(Ah, bh, acc);
    acc = MFMA16(Ah, bl, acc);
    acc = MFMA16(Al, bh, acc);
  }
  float sv[4];
  act2<0, true>(acc, spv, Sg, 1, cb, l4, l15, sv);
}

// global flat epoch barrier over 128 blocks (AGENT counter, bounded poll)
__device__ __forceinline__ void gflat(u32 *cnt, u32 &ep, u32 &pb) {
  wait_vm();
  __syncthreads();
  ep += 128u;
  if (threadIdx.x == 0) {
    __hip_atomic_fetch_add(&cnt[512], 1u, __ATOMIC_RELAXED, __HIP_MEMORY_SCOPE_AGENT);
    bool ok = false;
    for (u32 i = 0; i < pb; ++i) {
      u32 v = __hip_atomic_load(&cnt[512], __ATOMIC_RELAXED, __HIP_MEMORY_SCOPE_AGENT);
      if ((int)(v - ep) >= 0) { ok = true; break; }
      __builtin_amdgcn_s_sleep(2);
    }
    if (!ok) pb = 4096u;
  }
  __syncthreads();
}

// per-group epoch barrier: 16 participants, flat AGENT counter, bounded poll
__device__ __forceinline__ void grbar(u32 *gc, u32 &tep, u32 &pb) {
  wait_vm();   // each wave drains its sc-stores to LLC before arrival
  __syncthreads();
  tep += 16u;
  if (threadIdx.x == 0) {
    __hip_atomic_fetch_add(gc, 1u, __ATOMIC_RELAXED, __HIP_MEMORY_SCOPE_AGENT);
    bool ok = false;
    for (u32 i = 0; i < pb; ++i) {
      u32 v = __hip_atomic_load(gc, __ATOMIC_RELAXED, __HIP_MEMORY_SCOPE_AGENT);
      if ((int)(v - tep) >= 0) { ok = true; break; }
      __builtin_amdgcn_s_sleep(2);
    }
    if (!ok) pb = 4096u;
  }
  __syncthreads();
}

__global__ __launch_bounds__(256, 1) void darts_rnn(
    const float *__restrict__ xin, const float *__restrict__ h0in,
    const float *__restrict__ W0, const float *__restrict__ Wsi,
    float *__restrict__ out, u16 *__restrict__ wsu) {
  __shared__ u16 smem[2][16384];   // two 32KB staging panels
  u32 *cnt = (u32 *)wsu;
  u16 *Wh = wsu + 4096;            // byte 8192
  u16 *Wl = Wh + 5242880;
  u16 *Tbase = Wl + 5242880;

  const int tid = threadIdx.x, bid = blockIdx.x;
  const int ln = tid & 63, wid = tid >> 6;
  const int l15 = ln & 15, l4 = ln >> 4;
  const int g = bid >> 4;                 // group = row-tile 0..7
  const int cb = (bid & 15) * 4 + wid;    // wave's column tile 0..63
  const int trow0 = g * 16;
  u16 *Sg = Tbase + g * 131072;           // 8 slots x 16384
  u32 *gc = cnt + 1024 + g * 64;

  u32 ep = 0, pb = 1u << 24;

  // ---- hygiene: write back dirty ws lines, then invalidate L2 (round-4) ----
  if (wid == 0) asm volatile("buffer_wbl2 sc1" ::: "memory");
  wait_vm();
  gflat(cnt, ep, pb);
  if (wid == 0) asm volatile("buffer_inv sc1" ::: "memory");
  wait_vm();
  gflat(cnt, ep, pb);

  // ---- P0: weight hi/lo split into fragment layout (sc1 stores, LLC) ----
  for (int idx = bid * 256 + tid; idx < 5242880; idx += 32768) {
    int mk = idx >> 10, oc = idx & 1023;
    int m, k;
    if (mk < 1024) { m = 0; k = mk; } else { m = 1 + ((mk - 1024) >> 9); k = (mk - 1024) & 511; }
    float v = (m == 0) ? W0[k * 1024 + oc] : Wsi[((m - 1) * 512 + k) * 1024 + oc];
    int colp = (oc < 512) ? (oc * 2) : ((oc - 512) * 2 + 1);  // interleave c,h cols
    int cbw = colp >> 4;
    int kc = k >> 5;
    int lnn = (colp & 15) + ((k >> 3) & 3) * 16;
    int el = k & 7;
    int lineBase = (m == 0) ? (cbw * 32 + kc) : (cbw * 16 + kc);  // W0: K=1024
    int e = mbase(m) + (lineBase * 64 + lnn) * 8 + el;
    u16 hi, lo; splitbf(v, hi, lo);
    st16_sc(Wh + e, hi);
    st16_sc(Wl + e, lo);
  }
  // ---- h0 -> group slot 0 (redundant across the 16 members, benign) ----
  for (int i = tid; i < 8192; i += 256) {
    int row = i >> 9, k = i & 511;
    u16 hi, lo;
    splitbf(h0in[(trow0 + row) * 512 + k], hi, lo);
    u16 *p = Sg + goffG(0, row, k);
    st16_sc(p, hi);
    st16_sc(p + 8192, lo);
  }
  gflat(cnt, ep, pb);   // weights + all group panels ready, everywhere

  u32 tep = 0;
  float d0[4], d1[4];
  for (int t = 0; t < 256; ++t) {
    // ---- round A: s0 <- W0 on [x_t | h] ----
    stage_panel(Sg, 0, smem[0], tid);
    __syncthreads();
    roundA(xin, t, trow0, Wh, Wl, Sg, smem[0], cb, ln, l4, l15);
    grbar(gc, tep, pb);
    // ---- round B: s1 <- Ws0(sigmoid) on s0 ----
    stage_panel(Sg, 1, smem[0], tid);
    __syncthreads();
    gemm512<1, 1, false, true>(Wh, Wl, Sg, smem[0], 1, 1, 2, 2, cb, ln, l4, l15, d0, d1);
    grbar(gc, tep, pb);
    // ---- round C: s2<-Ws1(relu), s4<-Ws3(ident), s3<-Ws2(relu); A = s1 ----
    stage_panel(Sg, 2, smem[0], tid);
    __syncthreads();
    gemm512<2, 3, true, true>(Wh, Wl, Sg, smem[0], 2, 4, 3, 5, cb, ln, l4, l15, d0, d1);
    gemm512<2, 2, false, true>(Wh, Wl, Sg, smem[0], 3, 3, 4, 4, cb, ln, l4, l15, d0, d1);
    grbar(gc, tep, pb);
    // ---- round D: s5<-Ws4(tanh) on s2; s7<-Ws6(tanh) on s3 ----
    stage_panel(Sg, 3, smem[0], tid);
    stage_panel(Sg, 4, smem[1], tid);
    __syncthreads();
    gemm512<0, 0, false, true>(Wh, Wl, Sg, smem[0], 5, 5, 6, 6, cb, ln, l4, l15, d0, d1);
    gemm512<0, 0, false, true>(Wh, Wl, Sg, smem[1], 7, 7, 7, 7, cb, ln, l4, l15, d0, d1);
    grbar(gc, tep, pb);
    // ---- round E: s6<-Ws5(sig), s8<-Ws7(relu) on s5; mean -> out, h ----
    stage_panel(Sg, 6, smem[0], tid);
    __syncthreads();
    {
      float sv6[4], sv8[4];
      gemm512<1, 2, true, false>(Wh, Wl, Sg, smem[0], 6, 8, 0, 0, cb, ln, l4, l15, sv6, sv8);
      u32 mh[6][4], ml[6][4];
#pragma unroll
      for (int s = 0; s < 6; ++s)
#pragma unroll
        for (int j = 0; j < 4; ++j) {
          const u16 *p = Sg + goffG(s + 2, l4 * 4 + j, cb * 8 + (l15 >> 1));
          issue_ldu16_sc(mh[s][j], p);
          issue_ldu16_sc(ml[s][j], p + 8192);
        }
      wait_vm();
      if ((l15 & 1) == 0) {
#pragma unroll
        for (int j = 0; j < 4; ++j) {
          float sum = sv6[j] + sv8[j];
#pragma unroll
          for (int s = 0; s < 6; ++s) sum += bf2f(mh[s][j]) + bf2f(ml[s][j]);
          float hnew = sum * 0.125f;
          int row = l4 * 4 + j, scol = cb * 8 + (l15 >> 1);
          out[t * 65536 + (trow0 + row) * 512 + scol] = hnew;
          if (t == 255) out[16777216 + (trow0 + row) * 512 + scol] = hnew;
          u16 hi, lo; splitbf(hnew, hi, lo);
          u16 *p = Sg + goffG(0, row, scol);
          st16_sc(p, hi);
          st16_sc(p + 8192, lo);
        }
      }
    }
    grbar(gc, tep, pb);
  }
}

extern "C" void kernel_launch(void *const *d_in, const int *in_sizes, int n_in,
                              void *d_out, int out_size, void *d_ws, size_t ws_size,
                              hipStream_t stream) {
  const float *x = (const float *)d_in[0];
  const float *h0 = (const float *)d_in[1];
  const float *W0 = (const float *)d_in[2];
  const float *Ws = (const float *)d_in[3];
  float *out = (float *)d_out;
  u16 *ws = (u16 *)d_ws;

  hipMemsetAsync(d_ws, 0, 8192, stream);  // zero counters

  void *args[] = {(void *)&x, (void *)&h0, (void *)&W0, (void *)&Ws, (void *)&out, (void *)&ws};
  hipError_t err = hipLaunchCooperativeKernel((void *)darts_rnn, dim3(128), dim3(256),
                                              args, 0, stream);
  if (err != hipSuccess) {
    (void)hipGetLastError();
    darts_rnn<<<dim3(128), dim3(256), 0, stream>>>(x, h0, W0, Ws, out, ws);
  }
}